// Round 9
// baseline (346.268 us; speedup 1.0000x reference)
//
#include <hip/hip_runtime.h>
#include <hip/hip_fp16.h>
#include <stdint.h>

#define BB 512
#define TT 1024
#define II 15
#define HH 64
#define OO 11

typedef __fp16 half2v __attribute__((ext_vector_type(2)));
typedef _Float16 half8 __attribute__((ext_vector_type(8)));
typedef float floatx4 __attribute__((ext_vector_type(4)));
typedef int int4v __attribute__((ext_vector_type(4)));

union PK { int i; half2v h; float f; };

__device__ __forceinline__ half2v i2h2(int v) { PK u; u.i = v; return u.h; }
__device__ __forceinline__ int h22i(half2v v) { PK u; u.h = v; return u.i; }

__device__ __forceinline__ float FDOT2(half2v a, half2v b, float c) {
    return __builtin_amdgcn_fdot2(a, b, c, false);
}

// TWO batches per wave -> 256 waves = 1 wave/CU, halving per-CU LDS-pipe
// pressure (R7 had 2 waves/CU x 11 DS ops/step serializing on one pipe).
// Lane l: half = l>>5 selects the batch, c = l&31; lane computes the
// adjacent output pair {2c, 2c+1} of its batch.
// Per step DS program order: 8 uniform-address b128 h-reads (per-half
// broadcast; 2 addrs on same banks = 2-way = free) -> 1 packed b32 h-write
// -> 2 b128 x-reads for t+1. xproj(t+1) computed during step t.
__global__ __launch_bounds__(64) void rnn_rec(
    const float* __restrict__ x, const float* __restrict__ W_ih,
    const float* __restrict__ b_ih, const float* __restrict__ W_hh,
    const float* __restrict__ b_hh, _Float16* __restrict__ hs,
    float* __restrict__ h_last)
{
    // xbuf[bhalf][dblbuf][step*8] packed f16 pairs of x (+1.0 bias slot)
    __shared__ __align__(16) int xbuf[2][2][64 * 8];
    __shared__ __align__(16) int hbuf[64];   // [half*32 + c] = (h[2c],h[2c+1])
    const int lane = threadIdx.x;
    const int half = lane >> 5;
    const int c = lane & 31;
    const int b = blockIdx.x * 2 + half;
    const int o0 = 2 * c, o1 = 2 * c + 1;

    // recurrent weights for both outputs: wh*[p] = (W[o][2p], W[o][2p+1])
    half2v wh0[32], wh1[32];
#pragma unroll
    for (int p = 0; p < 32; ++p) {
        wh0[p] = __builtin_amdgcn_cvt_pkrtz(W_hh[o0 * HH + 2 * p],
                                            W_hh[o0 * HH + 2 * p + 1]);
        wh1[p] = __builtin_amdgcn_cvt_pkrtz(W_hh[o1 * HH + 2 * p],
                                            W_hh[o1 * HH + 2 * p + 1]);
    }
    // input weights; pair 7 = (w14, bias) matching x pair (x14, 1.0)
    half2v wx0[8], wx1[8];
#pragma unroll
    for (int j = 0; j < 7; ++j) {
        wx0[j] = __builtin_amdgcn_cvt_pkrtz(W_ih[o0 * II + 2 * j],
                                            W_ih[o0 * II + 2 * j + 1]);
        wx1[j] = __builtin_amdgcn_cvt_pkrtz(W_ih[o1 * II + 2 * j],
                                            W_ih[o1 * II + 2 * j + 1]);
    }
    wx0[7] = __builtin_amdgcn_cvt_pkrtz(W_ih[o0 * II + 14],
                                        b_ih[o0] + b_hh[o0]);
    wx1[7] = __builtin_amdgcn_cvt_pkrtz(W_ih[o1 * II + 14],
                                        b_ih[o1] + b_hh[o1]);

    const float* xb0 = x + (size_t)(blockIdx.x * 2) * TT * II;
    const float* xb1 = x + (size_t)(blockIdx.x * 2 + 1) * TT * II;
    int* hrow = (int*)(hs + (size_t)b * TT * HH) + c;  // pair slot c, step pitch 32

    // stage chunk 0 for both batches: lane ts packs x[bq][ts][0..14] -> 8 pairs
    {
#pragma unroll
        for (int q = 0; q < 2; ++q) {
            const float* xq = q ? xb1 : xb0;
            float cf[II];
#pragma unroll
            for (int i = 0; i < II; ++i) cf[i] = xq[lane * II + i];
            int4v p0, p1;
            p0.x = h22i(__builtin_amdgcn_cvt_pkrtz(cf[0], cf[1]));
            p0.y = h22i(__builtin_amdgcn_cvt_pkrtz(cf[2], cf[3]));
            p0.z = h22i(__builtin_amdgcn_cvt_pkrtz(cf[4], cf[5]));
            p0.w = h22i(__builtin_amdgcn_cvt_pkrtz(cf[6], cf[7]));
            p1.x = h22i(__builtin_amdgcn_cvt_pkrtz(cf[8], cf[9]));
            p1.y = h22i(__builtin_amdgcn_cvt_pkrtz(cf[10], cf[11]));
            p1.z = h22i(__builtin_amdgcn_cvt_pkrtz(cf[12], cf[13]));
            p1.w = h22i(__builtin_amdgcn_cvt_pkrtz(cf[14], 1.0f));
            *(int4v*)&xbuf[q][0][lane * 8] = p0;
            *(int4v*)&xbuf[q][0][lane * 8 + 4] = p1;
        }
    }
    hbuf[lane] = 0;   // h(-1) = 0 for both batches

    // xproj seeds for step 0 (4 chains per output)
    float xa0[4], xa1[4];
    {
        const int4v xv0 = *(const int4v*)&xbuf[half][0][0];
        const int4v xv1 = *(const int4v*)&xbuf[half][0][4];
        xa0[0] = FDOT2(i2h2(xv0.x), wx0[0], 0.0f);
        xa0[1] = FDOT2(i2h2(xv0.y), wx0[1], 0.0f);
        xa0[2] = FDOT2(i2h2(xv0.z), wx0[2], 0.0f);
        xa0[3] = FDOT2(i2h2(xv0.w), wx0[3], 0.0f);
        xa0[0] = FDOT2(i2h2(xv1.x), wx0[4], xa0[0]);
        xa0[1] = FDOT2(i2h2(xv1.y), wx0[5], xa0[1]);
        xa0[2] = FDOT2(i2h2(xv1.z), wx0[6], xa0[2]);
        xa0[3] = FDOT2(i2h2(xv1.w), wx0[7], xa0[3]);
        xa1[0] = FDOT2(i2h2(xv0.x), wx1[0], 0.0f);
        xa1[1] = FDOT2(i2h2(xv0.y), wx1[1], 0.0f);
        xa1[2] = FDOT2(i2h2(xv0.z), wx1[2], 0.0f);
        xa1[3] = FDOT2(i2h2(xv0.w), wx1[3], 0.0f);
        xa1[0] = FDOT2(i2h2(xv1.x), wx1[4], xa1[0]);
        xa1[1] = FDOT2(i2h2(xv1.y), wx1[5], xa1[1]);
        xa1[2] = FDOT2(i2h2(xv1.z), wx1[6], xa1[2]);
        xa1[3] = FDOT2(i2h2(xv1.w), wx1[7], xa1[3]);
    }

    float h0 = 0.0f, h1 = 0.0f;

    auto step = [&](int t) {
        // broadcast reads of my batch's h(t-1): 8 b128, addr uniform per half
        int4v hb[8];
#pragma unroll
        for (int q = 0; q < 8; ++q)
            hb[q] = *(const int4v*)&hbuf[half * 32 + q * 4];

        float A0 = xa0[0], A1 = xa0[1], A2 = xa0[2], A3 = xa0[3];
        float B0 = xa1[0], B1 = xa1[1], B2 = xa1[2], B3 = xa1[3];
#pragma unroll
        for (int q = 0; q < 8; ++q) {
            A0 = FDOT2(i2h2(hb[q].x), wh0[4 * q + 0], A0);
            A1 = FDOT2(i2h2(hb[q].y), wh0[4 * q + 1], A1);
            A2 = FDOT2(i2h2(hb[q].z), wh0[4 * q + 2], A2);
            A3 = FDOT2(i2h2(hb[q].w), wh0[4 * q + 3], A3);
            B0 = FDOT2(i2h2(hb[q].x), wh1[4 * q + 0], B0);
            B1 = FDOT2(i2h2(hb[q].y), wh1[4 * q + 1], B1);
            B2 = FDOT2(i2h2(hb[q].z), wh1[4 * q + 2], B2);
            B3 = FDOT2(i2h2(hb[q].w), wh1[4 * q + 3], B3);
        }
        h0 = fmaxf((A0 + A1) + (A2 + A3), 0.0f);
        h1 = fmaxf((B0 + B1) + (B2 + B3), 0.0f);
        const int pk = h22i(__builtin_amdgcn_cvt_pkrtz(h0, h1));
        hbuf[half * 32 + c] = pk;              // publish pair (DS op #9)

        // x pairs for step t+1 (DS ops #10,#11 — after the h write)
        const int tn = t + 1;
        const int* xp = &xbuf[half][(tn >> 6) & 1][(tn & 63) * 8];
        const int4v xv0 = *(const int4v*)xp;
        const int4v xv1 = *(const int4v*)(xp + 4);

        hrow[(size_t)t * 32] = pk;             // 2x128B contiguous global store

        // xproj for t+1 (fills residual stall)
        xa0[0] = FDOT2(i2h2(xv0.x), wx0[0], 0.0f);
        xa0[1] = FDOT2(i2h2(xv0.y), wx0[1], 0.0f);
        xa0[2] = FDOT2(i2h2(xv0.z), wx0[2], 0.0f);
        xa0[3] = FDOT2(i2h2(xv0.w), wx0[3], 0.0f);
        xa0[0] = FDOT2(i2h2(xv1.x), wx0[4], xa0[0]);
        xa0[1] = FDOT2(i2h2(xv1.y), wx0[5], xa0[1]);
        xa0[2] = FDOT2(i2h2(xv1.z), wx0[6], xa0[2]);
        xa0[3] = FDOT2(i2h2(xv1.w), wx0[7], xa0[3]);
        xa1[0] = FDOT2(i2h2(xv0.x), wx1[0], 0.0f);
        xa1[1] = FDOT2(i2h2(xv0.y), wx1[1], 0.0f);
        xa1[2] = FDOT2(i2h2(xv0.z), wx1[2], 0.0f);
        xa1[3] = FDOT2(i2h2(xv0.w), wx1[3], 0.0f);
        xa1[0] = FDOT2(i2h2(xv1.x), wx1[4], xa1[0]);
        xa1[1] = FDOT2(i2h2(xv1.y), wx1[5], xa1[1]);
        xa1[2] = FDOT2(i2h2(xv1.z), wx1[6], xa1[2]);
        xa1[3] = FDOT2(i2h2(xv1.w), wx1[7], xa1[3]);
    };

    for (int tc = 0; tc < TT; tc += 64) {
        // global prefetch of both batches' next chunk
        const int tnb = (tc + 64 < TT) ? (tc + 64) : tc;
        float nf0[II], nf1[II];
#pragma unroll
        for (int i = 0; i < II; ++i)
            nf0[i] = xb0[(size_t)(tnb + lane) * II + i];
#pragma unroll
        for (int i = 0; i < II; ++i)
            nf1[i] = xb1[(size_t)(tnb + lane) * II + i];

        for (int to = 0; to < 32; to += 8)
#pragma unroll
            for (int u = 0; u < 8; ++u) step(tc + to + u);

        // commit prefetched chunks (t+1 reads touch them only from ts=63)
        {
            const int cb = ((tc >> 6) + 1) & 1;
#pragma unroll
            for (int q = 0; q < 2; ++q) {
                const float* nf = q ? nf1 : nf0;
                int4v p0, p1;
                p0.x = h22i(__builtin_amdgcn_cvt_pkrtz(nf[0], nf[1]));
                p0.y = h22i(__builtin_amdgcn_cvt_pkrtz(nf[2], nf[3]));
                p0.z = h22i(__builtin_amdgcn_cvt_pkrtz(nf[4], nf[5]));
                p0.w = h22i(__builtin_amdgcn_cvt_pkrtz(nf[6], nf[7]));
                p1.x = h22i(__builtin_amdgcn_cvt_pkrtz(nf[8], nf[9]));
                p1.y = h22i(__builtin_amdgcn_cvt_pkrtz(nf[10], nf[11]));
                p1.z = h22i(__builtin_amdgcn_cvt_pkrtz(nf[12], nf[13]));
                p1.w = h22i(__builtin_amdgcn_cvt_pkrtz(nf[14], 1.0f));
                *(int4v*)&xbuf[q][cb][lane * 8] = p0;
                *(int4v*)&xbuf[q][cb][lane * 8 + 4] = p1;
            }
        }

        for (int to = 32; to < 64; to += 8)
#pragma unroll
            for (int u = 0; u < 8; ++u) step(tc + to + u);
    }
    h_last[(size_t)b * HH + o0] = h0;
    h_last[(size_t)b * HH + o1] = h1;
}

// Decoder: one 16x16x64 tile per wave (16 consecutive (b,t) rows of one batch).
// hs read: 2KB contiguous per wave; out store: 704B contiguous per tile.
__global__ __launch_bounds__(256) void rnn_decode(
    const _Float16* __restrict__ hs, const float* __restrict__ W_dec,
    const float* __restrict__ b_dec, float* __restrict__ out)
{
    __shared__ __align__(16) _Float16 wl[16 * HH];
    const int tid = threadIdx.x;
    for (int i = tid; i < 16 * HH; i += 256)
        wl[i] = (_Float16)((i < OO * HH) ? W_dec[i] : 0.0f);
    __syncthreads();

    const int lane = tid & 63;
    const int wid  = tid >> 6;
    const int col  = lane & 15;
    const int quad = lane >> 4;
    const float bd = (col < OO) ? b_dec[col] : 0.0f;

    half8 bf0 = *(const half8*)&wl[col * HH + quad * 8];
    half8 bf1 = *(const half8*)&wl[col * HH + 32 + quad * 8];

    const size_t tile = (size_t)blockIdx.x * 4 + wid;   // 0..32767
    const size_t btb = tile * 16;
    const _Float16* ap = hs + (btb + (size_t)col) * HH + quad * 8;
    half8 a0 = *(const half8*)ap;
    half8 a1 = *(const half8*)(ap + 32);

    floatx4 acc = {0.0f, 0.0f, 0.0f, 0.0f};
    acc = __builtin_amdgcn_mfma_f32_16x16x32_f16(a0, bf0, acc, 0, 0, 0);
    acc = __builtin_amdgcn_mfma_f32_16x16x32_f16(a1, bf1, acc, 0, 0, 0);

    if (col < OO) {
#pragma unroll
        for (int r = 0; r < 4; ++r) {
            const size_t row = btb + (size_t)(quad * 4 + r);
            out[row * OO + col] = fmaxf(acc[r] + bd, 0.0f);
        }
    }
}

extern "C" void kernel_launch(void* const* d_in, const int* in_sizes, int n_in,
                              void* d_out, int out_size, void* d_ws, size_t ws_size,
                              hipStream_t stream) {
    const float* x     = (const float*)d_in[0];
    const float* W_ih  = (const float*)d_in[1];
    const float* b_ih  = (const float*)d_in[2];
    const float* W_hh  = (const float*)d_in[3];
    const float* b_hh  = (const float*)d_in[4];
    const float* W_dec = (const float*)d_in[5];
    const float* b_dec = (const float*)d_in[6];

    float* out    = (float*)d_out;
    float* h_last = out + (size_t)BB * TT * OO;   // second tuple output
    _Float16* hs  = (_Float16*)d_ws;              // [B][T][H] f16, 64 MiB

    rnn_rec<<<BB / 2, 64, 0, stream>>>(x, W_ih, b_ih, W_hh, b_hh, hs, h_last);
    rnn_decode<<<8192, 256, 0, stream>>>(hs, W_dec, b_dec, out);
}